// Round 1
// baseline (241.863 us; speedup 1.0000x reference)
//
#include <hip/hip_runtime.h>
#include <hip/hip_bf16.h>
#include <cstdint>

#define BATCH 16
#define SEQ 2048
#define EMB 512
#define FFN 2048
#define NQ 8
#define M_TOTAL (BATCH * SEQ)   // 32768

#define BM 128
#define BN 256
#define BK 32
#define NTHREADS 512            // 8 waves: 2 (m) x 4 (n), each wave -> 64x64

typedef __attribute__((ext_vector_type(8))) short short8;   // 8 bf16 = 4 VGPRs (MFMA A/B frag)
typedef __attribute__((ext_vector_type(4))) float float4v;  // MFMA C/D frag

// ---- prep: W2 fp32 -> bf16 (row-major [EMB][FFN], K-contiguous) ----
__global__ __launch_bounds__(256) void prep_w2(const float* __restrict__ W2,
                                               __hip_bfloat16* __restrict__ w2b) {
    int idx = (blockIdx.x * 256 + threadIdx.x) * 4;  // 1048576 elems / 4
    float4 v = *(const float4*)&W2[idx];
    *(__hip_bfloat162*)&w2b[idx]     = __float22bfloat162_rn(make_float2(v.x, v.y));
    *(__hip_bfloat162*)&w2b[idx + 2] = __float22bfloat162_rn(make_float2(v.z, v.w));
}

// ---- fused main: q=cos(2x+theta) staged once; h generated inline (never hits HBM);
//      out-tile 128x256 via 16x16x32 bf16 MFMA ----
__global__ __launch_bounds__(NTHREADS) void ffq_main(
    const float* __restrict__ x,         // [M_TOTAL][EMB], only cols 0..7 used
    const float* __restrict__ theta,     // [8]
    const float* __restrict__ W1,        // [FFN][8] fp32
    const __hip_bfloat16* __restrict__ w2b, // [EMB][FFN] bf16
    float* __restrict__ out)             // [M_TOTAL][EMB]
{
    __shared__ __hip_bfloat16 Asm[BM * BK];   // 8 KB  [m][k] k-contig (h tile, bf16)
    __shared__ __hip_bfloat16 Bsm[BN * BK];   // 16 KB [n][k] k-contig (W2 tile)
    __shared__ float          qs[NQ][BM];     // 4 KB  q transposed: [j][m]
    __shared__ __hip_bfloat16 w1s[FFN * NQ];  // 32 KB whole W1 as bf16 [f][j]

    const int t  = threadIdx.x;
    const int m0 = blockIdx.x * BM;
    const int n0 = blockIdx.y * BN;

    // ---- stage q (compute cos inline; reads only 32 B per x row) ----
    for (int i = 0; i < (BM * NQ) / NTHREADS; ++i) {      // 2 iters
        int idx = i * NTHREADS + t;                        // 0..1023
        int m = idx >> 3, j = idx & 7;
        float xv = x[(size_t)(m0 + m) * EMB + j];
        qs[j][m] = cosf(2.0f * xv + theta[j]);
    }
    // ---- stage whole W1 -> bf16 LDS ----
    for (int i = 0; i < (FFN * NQ / 2) / NTHREADS; ++i) {  // 16 iters, 2 floats each
        int p = i * NTHREADS + t;                          // pair index
        float2 v = *(const float2*)&W1[p * 2];
        *(__hip_bfloat162*)&w1s[p * 2] = __float22bfloat162_rn(v);
    }
    __syncthreads();

    const int wave = t >> 6, lane = t & 63;
    const int wm = wave >> 2, wn = wave & 3;   // wave tile origin: (wm*64, wn*64)
    const int quad = lane >> 4, l16 = lane & 15;

    float4v acc[16];
#pragma unroll
    for (int i = 0; i < 16; ++i) acc[i] = (float4v)0.0f;

    for (int k0 = 0; k0 < FFN; k0 += BK) {                 // 64 iterations
        __syncthreads();  // previous iter's tiles fully consumed

        // ---- async stage B tile: [BN][BK] bf16 = 16 KB = 1024 x 16B chunks ----
#pragma unroll
        for (int i = 0; i < 2; ++i) {
            int c = i * NTHREADS + t;              // chunk id; per-wave contiguous => lds = base + lane*16
            int n = c >> 2, ko = (c & 3) * 8;
            const __hip_bfloat16* g = w2b + (size_t)(n0 + n) * FFN + k0 + ko;
            __hip_bfloat16* l = Bsm + c * 8;
            __builtin_amdgcn_global_load_lds(
                (const __attribute__((address_space(1))) unsigned int*)g,
                (__attribute__((address_space(3))) unsigned int*)(uintptr_t)l,
                16, 0, 0);
        }

        // ---- generate A tile (h, bf16): wave handles f = k0 + wave*4 .. +3 ----
        const int fb = k0 + wave * 4;
        float w1v[4][8];
#pragma unroll
        for (int r = 0; r < 4; ++r) {
            short8 row = *(const short8*)&w1s[(fb + r) * NQ];   // broadcast read (16 B)
#pragma unroll
            for (int j = 0; j < 8; ++j) {
                unsigned int u = ((unsigned int)(unsigned short)row[j]) << 16;
                w1v[r][j] = __builtin_bit_cast(float, u);
            }
        }
#pragma unroll
        for (int it = 0; it < 2; ++it) {
            int m = it * 64 + lane;                // stride-1 across lanes -> conflict-free qs reads
            float h0 = 0.f, h1 = 0.f, h2 = 0.f, h3 = 0.f;
#pragma unroll
            for (int j = 0; j < 8; ++j) {
                float qj = qs[j][m];
                h0 += qj * w1v[0][j];
                h1 += qj * w1v[1][j];
                h2 += qj * w1v[2][j];
                h3 += qj * w1v[3][j];
            }
            __hip_bfloat162 p0 = __float22bfloat162_rn(make_float2(fmaxf(h0, 0.f), fmaxf(h1, 0.f)));
            __hip_bfloat162 p1 = __float22bfloat162_rn(make_float2(fmaxf(h2, 0.f), fmaxf(h3, 0.f)));
            int ab = m * BK + wave * 4;
            *(__hip_bfloat162*)&Asm[ab]     = p0;
            *(__hip_bfloat162*)&Asm[ab + 2] = p1;
        }

        __syncthreads();  // A written + B arrived (compiler drains vmcnt before barrier)

        // ---- fragments + MFMA ----
        short8 af[4], bfr[4];
        const int am = wm * 64 + l16;
        const int bn = wn * 64 + l16;
#pragma unroll
        for (int fm = 0; fm < 4; ++fm)
            af[fm] = *(const short8*)&Asm[(am + fm * 16) * BK + quad * 8];
#pragma unroll
        for (int fn = 0; fn < 4; ++fn)
            bfr[fn] = *(const short8*)&Bsm[(bn + fn * 16) * BK + quad * 8];
#pragma unroll
        for (int fm = 0; fm < 4; ++fm)
#pragma unroll
            for (int fn = 0; fn < 4; ++fn)
                acc[fm * 4 + fn] = __builtin_amdgcn_mfma_f32_16x16x32_bf16(
                    af[fm], bfr[fn], acc[fm * 4 + fn], 0, 0, 0);
    }

    // ---- epilogue: D layout col=lane&15 (n), row=quad*4+reg (m) ----
    const int om = m0 + wm * 64;
    const int on = n0 + wn * 64;
#pragma unroll
    for (int fm = 0; fm < 4; ++fm) {
#pragma unroll
        for (int fn = 0; fn < 4; ++fn) {
            float4v v = acc[fm * 4 + fn];
            int rbase = om + fm * 16 + quad * 4;
            int c     = on + fn * 16 + l16;
#pragma unroll
            for (int r = 0; r < 4; ++r)
                out[(size_t)(rbase + r) * EMB + c] = v[r];
        }
    }
}

extern "C" void kernel_launch(void* const* d_in, const int* in_sizes, int n_in,
                              void* d_out, int out_size, void* d_ws, size_t ws_size,
                              hipStream_t stream) {
    const float* x     = (const float*)d_in[0];
    const float* theta = (const float*)d_in[1];
    const float* W1    = (const float*)d_in[2];
    const float* W2    = (const float*)d_in[3];
    float* out = (float*)d_out;

    __hip_bfloat16* w2b = (__hip_bfloat16*)d_ws;   // 2 MiB of ws

    prep_w2<<<(EMB * FFN) / (256 * 4), 256, 0, stream>>>(W2, w2b);

    dim3 grid(M_TOTAL / BM, EMB / BN);             // 256 x 2 = 512 blocks
    ffq_main<<<grid, NTHREADS, 0, stream>>>(x, theta, W1, w2b, out);
}

// Round 3
// 176.408 us; speedup vs baseline: 1.3710x; 1.3710x over previous
//
#include <hip/hip_runtime.h>
#include <cstdint>

#define BATCH 16
#define SEQ 2048
#define EMB 512
#define FFN 2048
#define NQ 8
#define M_TOTAL (BATCH * SEQ)   // 32768

#define BM 128
#define BN 256
#define BK 32
#define NTHREADS 512            // 8 waves: 2 (m) x 4 (n), wave tile 64x64

typedef __attribute__((ext_vector_type(8))) short short8;   // 8 bf16 (MFMA A/B frag)
typedef __attribute__((ext_vector_type(4))) float float4v;  // MFMA C/D frag
typedef __attribute__((ext_vector_type(4))) unsigned int uint4v;

// fp32 -> bf16 bits, round-to-nearest-even (finite inputs)
static __device__ __forceinline__ unsigned int f2bf(float f) {
    unsigned int u = __builtin_bit_cast(unsigned int, f);
    return (u + 0x7fffu + ((u >> 16) & 1u)) >> 16;
}
static __device__ __forceinline__ unsigned int f2bf_pk(float lo, float hi) {
    return f2bf(lo) | (f2bf(hi) << 16);
}

// ---- prep: W2 fp32 -> bf16 (row-major [EMB][FFN], K-contiguous) ----
__global__ __launch_bounds__(256) void prep_w2(const float* __restrict__ W2,
                                               unsigned int* __restrict__ w2b) {
    int idx = (blockIdx.x * 256 + threadIdx.x) * 4;
    float4 v = *(const float4*)&W2[idx];
    w2b[idx / 2]     = f2bf_pk(v.x, v.y);
    w2b[idx / 2 + 1] = f2bf_pk(v.z, v.w);
}

// Swizzled LDS tile layout: row stride 32 bf16 (64 B = 4 chunks of 16 B).
// Logical k-chunk q lives at physical chunk q ^ ((row>>1)&3) -> frag reads
// (row = base + l16, chunk = quad) cover all 32 banks per 8-lane phase.

__global__ __launch_bounds__(NTHREADS) void ffq_main(
    const float* __restrict__ x,              // [M_TOTAL][EMB], cols 0..7 used
    const float* __restrict__ theta,          // [8]
    const float* __restrict__ W1,             // [FFN][8] fp32
    const unsigned short* __restrict__ w2b,   // [EMB][FFN] bf16 bits
    float* __restrict__ out)                  // [M_TOTAL][EMB]
{
    __shared__ unsigned short Asm[BM * BK];   // 8 KB  h tile, swizzled
    __shared__ unsigned short Bsm[BN * BK];   // 16 KB W2 tile, swizzled
    __shared__ unsigned short w1s[FFN * NQ];  // 32 KB whole W1 bf16 [f][j]

    const int t    = threadIdx.x;
    const int m0   = blockIdx.x * BM;
    const int n0   = blockIdx.y * BN;
    const int wave = t >> 6, lane = t & 63;
    const int quad = lane >> 4, l16 = lane & 15;
    const int wm   = wave >> 2, wn = wave & 3;

    // ---- stage whole W1 -> bf16 LDS ----
#pragma unroll
    for (int i = 0; i < (FFN * NQ / 2) / NTHREADS; ++i) {   // 16 iters
        int p = i * NTHREADS + t;
        float2 v = *(const float2*)&W1[p * 2];
        *(unsigned int*)&w1s[p * 2] = f2bf_pk(v.x, v.y);
    }

    // ---- per-wave persistent Q fragment (B-operand of h-gen MFMA) ----
    // wave g owns m rows g*16..g*16+15; lane l16 holds q[g*16+l16][j=0..7]
    // in quad 0 (K slots 0..7); quads 1..3 are ZERO so K=8..31 padding adds 0.
    short8 qfrag;
    {
        int qrow = m0 + wave * 16 + l16;
        const float* xr = x + (size_t)qrow * EMB;
        float4 xa = *(const float4*)xr;
        float4 xb = *(const float4*)(xr + 4);
        uint4v uq;
        uq[0] = f2bf_pk(__cosf(2.f * xa.x + theta[0]), __cosf(2.f * xa.y + theta[1]));
        uq[1] = f2bf_pk(__cosf(2.f * xa.z + theta[2]), __cosf(2.f * xa.w + theta[3]));
        uq[2] = f2bf_pk(__cosf(2.f * xb.x + theta[4]), __cosf(2.f * xb.y + theta[5]));
        uq[3] = f2bf_pk(__cosf(2.f * xb.z + theta[6]), __cosf(2.f * xb.w + theta[7]));
        qfrag = __builtin_bit_cast(short8, uq);
        if (quad != 0) qfrag = (short8)0;
    }

    float4v acc[16];
#pragma unroll
    for (int i = 0; i < 16; ++i) acc[i] = (float4v)0.0f;

    for (int k0 = 0; k0 < FFN; k0 += BK) {                  // 64 iterations
        __syncthreads();   // prev iter's tiles consumed (also covers w1s @k0=0)

        // ---- async stage B tile, source-swizzled; LDS dest lane-contiguous ----
#pragma unroll
        for (int i = 0; i < 2; ++i) {
            int c = i * NTHREADS + t;          // physical chunk id
            int n = c >> 2, s = c & 3;
            int qk = s ^ ((n >> 1) & 3);       // logical k-chunk stored at slot s
            const unsigned short* g = w2b + (size_t)(n0 + n) * FFN + k0 + qk * 8;
            __builtin_amdgcn_global_load_lds(
                (const __attribute__((address_space(1))) unsigned int*)g,
                (__attribute__((address_space(3))) unsigned int*)(uintptr_t)(Bsm + c * 8),
                16, 0, 0);
        }

        // ---- h-gen via MFMA: H[f][m] = sum_j W1[f][j] * q[m][j], then relu ----
        // A = W1 slice (lane l16 -> row f = k0+fh*16+l16; quads 1-3 read the
        // same finite data but multiply qfrag's zeros), B = qfrag.
        // C layout: row = quad*4+r -> f, col = l16 -> m. Each lane gets 4
        // consecutive f for one m -> one 8-byte store into swizzled Asm.
#pragma unroll
        for (int fh = 0; fh < 2; ++fh) {
            int f = k0 + fh * 16 + l16;
            short8 w1f = *(const short8*)&w1s[f * NQ];
            float4v hc = __builtin_amdgcn_mfma_f32_16x16x32_bf16(
                w1f, qfrag, (float4v)0.0f, 0, 0, 0);
            unsigned int p0 = f2bf_pk(fmaxf(hc[0], 0.f), fmaxf(hc[1], 0.f));
            unsigned int p1 = f2bf_pk(fmaxf(hc[2], 0.f), fmaxf(hc[3], 0.f));
            int m    = wave * 16 + l16;
            int qlog = fh * 2 + (quad >> 1);       // logical k-chunk of these 4 f
            int qph  = qlog ^ ((l16 >> 1) & 3);    // swizzled physical chunk
            unsigned long long pk = ((unsigned long long)p1 << 32) | p0;
            *(unsigned long long*)&Asm[m * 32 + qph * 8 + (quad & 1) * 4] = pk;
        }

        __syncthreads();   // Asm written + Bsm DMA drained

        // ---- conflict-free fragment loads ----
        short8 af[4], bfr[4];
#pragma unroll
        for (int fm = 0; fm < 4; ++fm) {
            int row = wm * 64 + fm * 16 + l16;
            int qph = quad ^ ((row >> 1) & 3);
            af[fm] = *(const short8*)&Asm[row * 32 + qph * 8];
        }
#pragma unroll
        for (int fn = 0; fn < 4; ++fn) {
            int row = wn * 64 + fn * 16 + l16;
            int qph = quad ^ ((row >> 1) & 3);
            bfr[fn] = *(const short8*)&Bsm[row * 32 + qph * 8];
        }

#pragma unroll
        for (int fm = 0; fm < 4; ++fm)
#pragma unroll
            for (int fn = 0; fn < 4; ++fn)
                acc[fm * 4 + fn] = __builtin_amdgcn_mfma_f32_16x16x32_bf16(
                    af[fm], bfr[fn], acc[fm * 4 + fn], 0, 0, 0);
    }

    // ---- epilogue: D layout col=lane&15 (n), row=quad*4+reg (m) ----
    const int om = m0 + wm * 64;
    const int on = n0 + wn * 64;
#pragma unroll
    for (int fm = 0; fm < 4; ++fm) {
#pragma unroll
        for (int fn = 0; fn < 4; ++fn) {
            float4v v = acc[fm * 4 + fn];
            int rbase = om + fm * 16 + quad * 4;
            int c     = on + fn * 16 + l16;
#pragma unroll
            for (int r = 0; r < 4; ++r)
                out[(size_t)(rbase + r) * EMB + c] = v[r];
        }
    }
}

extern "C" void kernel_launch(void* const* d_in, const int* in_sizes, int n_in,
                              void* d_out, int out_size, void* d_ws, size_t ws_size,
                              hipStream_t stream) {
    const float* x     = (const float*)d_in[0];
    const float* theta = (const float*)d_in[1];
    const float* W1    = (const float*)d_in[2];
    const float* W2    = (const float*)d_in[3];
    float* out = (float*)d_out;

    unsigned int* w2b = (unsigned int*)d_ws;   // 2 MiB of ws (bf16 bits, packed)

    prep_w2<<<(EMB * FFN) / (256 * 4), 256, 0, stream>>>(W2, w2b);

    dim3 grid(M_TOTAL / BM, EMB / BN);         // 256 x 2 = 512 blocks
    ffq_main<<<grid, NTHREADS, 0, stream>>>(x, theta, W1, (const unsigned short*)w2b, out);
}